// Round 12
// baseline (161.759 us; speedup 1.0000x reference)
//
#include <hip/hip_runtime.h>
#include <hip/hip_bf16.h>
#include <hip/hip_fp8.h>
#include <math.h>

#define GN 1024
#define GM 32
#define GD 512
#define NROW (GN*GM)   // 32768

// ---------------- ws layout (bytes) ----------------
#define WS_XF8   0ull                  // u8 [NROW][512] = 16777216 (row-major fp8)
#define WS_SF8   16777216ull           // u8 [GN][512]   =   524288
#define WS_INVSN 17301504ull           // f32 [GN]
#define WS_INVXN 17305600ull           // f32 [NROW]
#define WS_CSOWN 17436672ull           // f32 [NROW]
#define WS_PS    17567744ull           // f32 [NROW*16]

typedef __attribute__((ext_vector_type(4)))  int   i32x4;
typedef __attribute__((ext_vector_type(8)))  int   i32x8;
typedef __attribute__((ext_vector_type(16))) float f32x16;

__device__ inline unsigned char f32_to_e4m3(float f) {
    __hip_fp8_e4m3 q(f);               // OCP e4m3fn, saturating
    return (unsigned char)q.__x;
}

// ---------------------------------------------------------------------------
// Kernel A: per speaker n — centroid sums, norms, own-centroid cosine,
// plus row-major fp8 conversion of x and S. x read from HBM ONCE; staged in
// LDS (f32, 64 KB) for the phase-2 per-utterance reductions.
// grid GN blocks, 512 threads.
// ---------------------------------------------------------------------------
__global__ __launch_bounds__(512) void prep_kernel(
    const float* __restrict__ x, const float* __restrict__ wp,
    const float* __restrict__ bp, char* __restrict__ wsb)
{
    unsigned char* xf8 = (unsigned char*)(wsb + WS_XF8);
    unsigned char* Sf8 = (unsigned char*)(wsb + WS_SF8);
    float* invSn = (float*)(wsb + WS_INVSN);
    float* invxn = (float*)(wsb + WS_INVXN);
    float* csown = (float*)(wsb + WS_CSOWN);

    const int n = blockIdx.x;
    const int d = threadIdx.x;           // 0..511 (= k index)
    const int lane = d & 63;
    const int wid  = d >> 6;             // 0..7

    __shared__ float sx[GM][GD];         // 64 KB: x panel, f32
    __shared__ float sS[GD];
    __shared__ float red[8];
    __shared__ float sSn2;

    const float* xn_ = x + (size_t)n * GM * GD;

    // phase 1: single global read of x; stage to LDS; column sum; fp8 image
    float Sd = 0.f;
    #pragma unroll
    for (int m = 0; m < GM; ++m) {
        float xv = xn_[m * GD + d];
        sx[m][d] = xv;
        Sd += xv;
        xf8[(size_t)(n * GM + m) * GD + d] = f32_to_e4m3(xv);
    }
    sS[d] = Sd;
    Sf8[(size_t)n * GD + d] = f32_to_e4m3(Sd);

    // ||S||^2
    float p = Sd * Sd;
    #pragma unroll
    for (int o = 32; o > 0; o >>= 1) p += __shfl_down(p, o);
    if (lane == 0) red[wid] = p;
    __syncthreads();
    if (d == 0) {
        float s = 0.f;
        #pragma unroll
        for (int i = 0; i < 8; ++i) s += red[i];
        sSn2 = s;
        invSn[n] = rsqrtf(s);
    }
    __syncthreads();

    // phase 2: per-utterance norms + dot(x, S) from LDS
    const float w0 = wp[0], b0 = bp[0];
    const float Sn2 = sSn2;
    #pragma unroll
    for (int mm = 0; mm < 4; ++mm) {
        const int m = wid + mm * 8;
        float xn2 = 0.f, dn = 0.f;
        #pragma unroll
        for (int j = 0; j < 8; ++j) {
            float xv = sx[m][lane + 64 * j];
            float sv = sS[lane + 64 * j];
            xn2 += xv * xv;
            dn  += xv * sv;
        }
        #pragma unroll
        for (int o = 32; o > 0; o >>= 1) {
            xn2 += __shfl_down(xn2, o);
            dn  += __shfl_down(dn, o);
        }
        if (lane == 0) {
            float ixn = rsqrtf(xn2);
            float en2 = Sn2 - 2.f * dn + xn2;          // ||S - x||^2
            float cosown = (dn - xn2) * ixn * rsqrtf(en2);
            csown[n * GM + m] = w0 * fmaxf(cosown, 1e-6f) + b0;
            invxn[n * GM + m] = ixn;
        }
    }
}

// ---------------------------------------------------------------------------
// Kernel B: fp8 MX-scaled MFMA GEMM G = x(32768x512) * S^T(512x1024).
// mfma_scale_f32_32x32x64_f8f6f4 with unit scales (e8m0 0x7F = 1.0): the
// 2x fp8 rate path, 8x fewer MFMA issues. 128x128 tile / BK=64 / 4 waves
// (2x2), wave tile 64x64 = 2x2 32x32 accs (f32x16 each). LDS chunk map:
// 16-B chunk c = q*256 + s*64 + lane (q = k-16B-half, s = 32-row sub-tile)
// -> staging is wave-uniform+lane*16 AND fragment reads are lane-linear
// 1 KB windows (conflict-free). fp8 image row-major; A and B share the
// same byte->k map so the instruction's internal k-mapping cancels.
// R9 drain schedule: per step vmcnt(0) + ONE raw s_barrier, STAGE before
// compute. 8 K-steps. XCD swizzle. Fused fixed-shift softmax epilogue on
// the 32x32 C/D layout (col=lane&31, row=(r&3)+8*(r>>2)+4*(lane>>5)).
// grid 2048 blocks, 256 threads.
// ---------------------------------------------------------------------------
__global__ __launch_bounds__(256) void gemm_kernel(
    const float* __restrict__ wp, const float* __restrict__ bp,
    char* __restrict__ wsb)
{
    const unsigned char* xf8 = (const unsigned char*)(wsb + WS_XF8);
    const unsigned char* Sf8 = (const unsigned char*)(wsb + WS_SF8);
    const float* invSn = (const float*)(wsb + WS_INVSN);
    const float* invxn = (const float*)(wsb + WS_INVXN);
    const float* csown = (const float*)(wsb + WS_CSOWN);
    float* ps = (float*)(wsb + WS_PS);

    // chunk c = q*256 + s*64 + l : byte offset c*16
    __shared__ __align__(16) unsigned char Ab[2][512][16];   // 16 KB
    __shared__ __align__(16) unsigned char Bb[2][512][16];   // 16 KB

    // XCD swizzle: hw xcd = bid & 7 owns row-panels [xcd*32, xcd*32+32)
    const int bid  = blockIdx.x;          // 0..2047
    const int u    = bid >> 3;            // 0..255
    const int rowp = (bid & 7) * 32 + (u >> 3);
    const int colp = u & 7;
    const int rbase = rowp * 128;
    const int cbase = colp * 128;

    const int t    = threadIdx.x;
    const int w    = t >> 6;
    const int lane = t & 63;
    const int wr   = w >> 1, wc = w & 1;   // wave tile 64x64

    f32x16 acc[2][2] = {};

    // staging: thread t stages chunks c = t (q=0) and c = 256+t (q=1),
    // sub s = w, lane-in-sub l = t&63, row = s*32 + (l&31), khalf h = bit5
    const int srow = w * 32 + (t & 31);
    const int ah   = ((t >> 5) & 1) * 32;          // k-half byte offset
    const unsigned char* agbase = xf8 + (size_t)(rbase + srow) * GD + ah;
    const unsigned char* bgbase = Sf8 + (size_t)(cbase + srow) * GD + ah;
    const int cb0 = w * 64;                        // chunk base, q=0
    const int cb1 = 256 + w * 64;                  // chunk base, q=1

#define STAGE(buf, ks)                                                        \
    do {                                                                      \
        const int kof_ = (ks) * 64;                                           \
        __builtin_amdgcn_global_load_lds(                                     \
            (const __attribute__((address_space(1))) void*)(agbase + kof_),   \
            (__attribute__((address_space(3))) void*)&Ab[buf][cb0][0],        \
            16, 0, 0);                                                        \
        __builtin_amdgcn_global_load_lds(                                     \
            (const __attribute__((address_space(1))) void*)(agbase + kof_ + 16), \
            (__attribute__((address_space(3))) void*)&Ab[buf][cb1][0],        \
            16, 0, 0);                                                        \
        __builtin_amdgcn_global_load_lds(                                     \
            (const __attribute__((address_space(1))) void*)(bgbase + kof_),   \
            (__attribute__((address_space(3))) void*)&Bb[buf][cb0][0],        \
            16, 0, 0);                                                        \
        __builtin_amdgcn_global_load_lds(                                     \
            (const __attribute__((address_space(1))) void*)(bgbase + kof_ + 16), \
            (__attribute__((address_space(3))) void*)&Bb[buf][cb1][0],        \
            16, 0, 0);                                                        \
    } while (0)

    auto compute = [&](int buf) {
        i32x8 af[2], bf[2];
        #pragma unroll
        for (int mi = 0; mi < 2; ++mi) {
            const int s = wr * 2 + mi;
            i32x4 lo = *(const i32x4*)&Ab[buf][s * 64 + lane][0];
            i32x4 hi = *(const i32x4*)&Ab[buf][256 + s * 64 + lane][0];
            af[mi] = __builtin_shufflevector(lo, hi, 0, 1, 2, 3, 4, 5, 6, 7);
        }
        #pragma unroll
        for (int nj = 0; nj < 2; ++nj) {
            const int s = wc * 2 + nj;
            i32x4 lo = *(const i32x4*)&Bb[buf][s * 64 + lane][0];
            i32x4 hi = *(const i32x4*)&Bb[buf][256 + s * 64 + lane][0];
            bf[nj] = __builtin_shufflevector(lo, hi, 0, 1, 2, 3, 4, 5, 6, 7);
        }
        #pragma unroll
        for (int mi = 0; mi < 2; ++mi)
            #pragma unroll
            for (int nj = 0; nj < 2; ++nj)
                acc[mi][nj] = __builtin_amdgcn_mfma_scale_f32_32x32x64_f8f6f4(
                    af[mi], bf[nj], acc[mi][nj], 0, 0,
                    0, 0x7F7F7F7F, 0, 0x7F7F7F7F);   // unit scales
    };

#define WAITVM0()  asm volatile("s_waitcnt vmcnt(0)" ::: "memory")
#define BARRIER()  asm volatile("s_barrier" ::: "memory")

#define KSTEP(ks)                                                             \
    do {                                                                      \
        WAITVM0();                                                            \
        BARRIER();                                                            \
        if ((ks) + 1 < 8) STAGE(((ks) + 1) & 1, (ks) + 1);                    \
        compute((ks) & 1);                                                    \
    } while (0)

    // prologue: 1 tile in flight
    STAGE(0, 0);

    KSTEP(0);  KSTEP(1);  KSTEP(2);  KSTEP(3);
    KSTEP(4);  KSTEP(5);  KSTEP(6);  KSTEP(7);

#undef KSTEP
#undef WAITVM0
#undef BARRIER
#undef STAGE

    // ---- fused epilogue: fixed-shift partial softmax, 32x32 C/D layout
    const float w0 = wp[0], b0 = bp[0];
    const float C = fmaxf(w0 * 1e-6f + b0, w0 + b0);   // logit upper bound
    const int pcol = colp * 2 + wc;                    // 0..15 partial slot
    const int h   = lane >> 5;
    const int c31 = lane & 31;
    float isn[2];
    #pragma unroll
    for (int nj = 0; nj < 2; ++nj)
        isn[nj] = invSn[cbase + wc * 64 + nj * 32 + c31];

    #pragma unroll
    for (int mi = 0; mi < 2; ++mi) {
        #pragma unroll
        for (int r = 0; r < 16; ++r) {
            const int row = rbase + wr * 64 + mi * 32
                          + (r & 3) + 8 * (r >> 2) + 4 * h;
            const float ixn = invxn[row];
            const float cso = csown[row];
            const int own = row >> 5;
            float se = 0.f;
            #pragma unroll
            for (int nj = 0; nj < 2; ++nj) {
                const int col = cbase + wc * 64 + nj * 32 + c31;
                float cs = w0 * fmaxf(acc[mi][nj][r] * ixn * isn[nj], 1e-6f) + b0;
                cs = (col == own) ? cso : cs;
                se += __expf(cs - C);
            }
            #pragma unroll
            for (int off = 1; off < 32; off <<= 1)
                se += __shfl_xor(se, off);
            if (c31 == 0)
                ps[(size_t)row * 16 + pcol] = se;
        }
    }
}

// ---------------------------------------------------------------------------
// Kernel C: combine 16 sum-partials per row (shared fixed shift C),
// loss = C + log(sum) - cs_own, mean-reduce into d_out[0].
// ---------------------------------------------------------------------------
__global__ __launch_bounds__(256) void finalize_kernel(
    const char* __restrict__ wsb, const float* __restrict__ wp,
    const float* __restrict__ bp, float* __restrict__ out)
{
    const float* csown = (const float*)(wsb + WS_CSOWN);
    const float* ps    = (const float*)(wsb + WS_PS);

    const float w0 = wp[0], b0 = bp[0];
    const float C = fmaxf(w0 * 1e-6f + b0, w0 + b0);

    const int row = blockIdx.x * 256 + threadIdx.x;
    float s = 0.f;
    #pragma unroll
    for (int i = 0; i < 16; ++i) s += ps[(size_t)row * 16 + i];
    float loss = C + logf(s) - csown[row];

    const int lane = threadIdx.x & 63;
    const int wid  = threadIdx.x >> 6;
    __shared__ float red[4];
    #pragma unroll
    for (int off = 32; off > 0; off >>= 1) loss += __shfl_down(loss, off);
    if (lane == 0) red[wid] = loss;
    __syncthreads();
    if (threadIdx.x == 0) {
        float sum = red[0] + red[1] + red[2] + red[3];
        atomicAdd(out, sum * (1.f / (GN * GM)));
    }
}

extern "C" void kernel_launch(void* const* d_in, const int* in_sizes, int n_in,
                              void* d_out, int out_size, void* d_ws, size_t ws_size,
                              hipStream_t stream)
{
    const float* x  = (const float*)d_in[0];
    const float* wp = (const float*)d_in[1];
    const float* bp = (const float*)d_in[2];
    float* out = (float*)d_out;
    char* wsb  = (char*)d_ws;

    hipMemsetAsync(d_out, 0, sizeof(float), stream);

    prep_kernel<<<GN, 512, 0, stream>>>(x, wp, bp, wsb);

    gemm_kernel<<<2048, 256, 0, stream>>>(wp, bp, wsb);

    finalize_kernel<<<128, 256, 0, stream>>>(wsb, wp, bp, out);
}